// Round 15
// baseline (316.229 us; speedup 1.0000x reference)
//
#include <hip/hip_runtime.h>
#include <hip/hip_bf16.h>

#define MODEL 2048
#define NHEAD 16
#define HDIM  128
#define BB    2
#define LL    2048
#define N1    (3*MODEL)      // 6144
#define MTOT  (BB*LL)        // 4096

typedef __hip_bfloat16 bf16;
typedef __attribute__((ext_vector_type(8))) short bf16x8;
typedef __attribute__((ext_vector_type(4))) float f32x4;

static __device__ __forceinline__ f32x4 mfma16(bf16x8 a, bf16x8 b, f32x4 c) {
  return __builtin_amdgcn_mfma_f32_16x16x32_bf16(a, b, c, 0, 0, 0);
}

// async global->LDS DMA, 16B per lane; LDS base wave-uniform, dest linear
static __device__ __forceinline__ void gl_lds16(const void* g, void* l) {
  __builtin_amdgcn_global_load_lds(
      (const __attribute__((address_space(1))) unsigned int*)g,
      (__attribute__((address_space(3))) unsigned int*)l, 16, 0, 0);
}

static __device__ __forceinline__ unsigned bfu(float x) {
  bf16 b = __float2bfloat16(x);
  return (unsigned)*reinterpret_cast<unsigned short*>(&b);
}

#define BARRIER __builtin_amdgcn_s_barrier()
#define SCHED0  __builtin_amdgcn_sched_barrier(0)
#define PRIO1 __builtin_amdgcn_s_setprio(1)
#define PRIO0 __builtin_amdgcn_s_setprio(0)

// ---------------- prep: f32 -> bf16 (vectorized x4) ----------------
__global__ void k_cvt(const float* __restrict__ in, bf16* __restrict__ out, int n4) {
  int i = blockIdx.x * blockDim.x + threadIdx.x;
  if (i < n4) {
    float4 v = ((const float4*)in)[i];
    bf16* o = out + (size_t)i * 4;
    o[0] = __float2bfloat16(v.x);
    o[1] = __float2bfloat16(v.y);
    o[2] = __float2bfloat16(v.z);
    o[3] = __float2bfloat16(v.w);
  }
}

// ---------------- prep: transpose f32 [R][C] -> bf16 [C][R] ----------------
__global__ __launch_bounds__(256)
void k_transpose(const float* __restrict__ in, bf16* __restrict__ out, int R, int C) {
  __shared__ float t[32][33];
  const int c0 = blockIdx.x * 32, r0 = blockIdx.y * 32;
  const int tx = threadIdx.x & 31;
  const int ty = threadIdx.x >> 5;   // 0..7
#pragma unroll
  for (int i = 0; i < 4; ++i)
    t[ty + 8*i][tx] = in[(size_t)(r0 + ty + 8*i) * C + c0 + tx];
  __syncthreads();
#pragma unroll
  for (int i = 0; i < 4; ++i)
    out[(size_t)(c0 + ty + 8*i) * R + r0 + tx] = __float2bfloat16(t[tx][ty + 8*i]);
}

// ====== r15 GEMM1: 256x256 tile, BK=64, 2-buffer double-buffer, 1 block/CU ==
// 8 waves 2Mx4N, wave output 128x64 (acc 8x4): MFMA:ds_read = 64:24 = 2.67
// (vs 1.33 of the 128^2 kernel) and only 32 K-tiles (half the sync count).
// LDS 128KB: buf b: A[256][128B] @ b*65536, B[256][128B] @ +32768.
// 128B-row swizzle (r4-VERIFIED, conflicts 0): read 16B-slot s_log at row r
// sits at phys byte-col (s_log*16) ^ ((r&7)<<4); staged via inverse-permuted
// SOURCE col ((l ^ (l>>3)) & 7)*8 bf16, linear gl_lds dest.
// Sync per tile (r8 lesson: distributed staging -> collective barrier):
// reads0; stage(t+1 -> buf^1); MFMA0; reads1; MFMA1; vmcnt(0); barrier.
// No manual lgkm waits: compiler auto-inserts fine-grained lgkmcnt for the
// ds_read->MFMA register deps and interleaves reads1 into MFMA0 (m97).
// Buffer safety: buf^1 was last read at tile t-1, all waves crossed that
// barrier before stage issues. Epilogue indexing r7-verified (BM=256 path).
template<int EPI>
__global__ __launch_bounds__(512, 2)
void k_gemmX(const bf16* __restrict__ A, const bf16* __restrict__ BT,
             int M, int N, int K,
             float* __restrict__ Cout, const float* __restrict__ bias,
             bf16* __restrict__ Qb, bf16* __restrict__ Kb, bf16* __restrict__ VTb,
             const float* __restrict__ cosT, const float* __restrict__ sinT)
{
  extern __shared__ char smem[];       // 131072 B
  const int tid = threadIdx.x;
  const int wid = tid >> 6, lane = tid & 63;
  const int wm = wid >> 2, wn = wid & 3;       // wave grid 2(M) x 4(N)
  const int lr = lane & 15, lkg = lane >> 4;

  // XCD chunk map (bid%8 = XCD): XCD=(mquarter,nhalf) owns (nby/4) m-tiles x
  // (nbx/2) n-tiles, m-inner traversal -> per-XCD A panel = 4MB (L2-fit).
  const int nby = M >> 8, nbx = N >> 8;
  const int mc  = nby >> 2;
  const int xcd = blockIdx.x & 7;
  const int i   = blockIdx.x >> 3;
  const int m0 = (((xcd >> 1) * mc) + (i % mc)) << 8;
  const int n0 = (((xcd & 1) * (nbx >> 1)) + (i / mc)) << 8;

  // staging source (r4-verified inverse swizzle), wave wid covers rows
  // wid*8 + 64*j + (lane>>3), phys slot lane&7
  const int srow = lane >> 3;
  const int scol = ((lane ^ (lane >> 3)) & 7) * 8;   // bf16 elems
  const bf16* Asrc = A  + (size_t)(m0 + wid*8 + srow) * K + scol;
  const bf16* Bsrc = BT + (size_t)(n0 + wid*8 + srow) * K + scol;

  auto stage = [&](int t, int buf) {
    const bf16* ga = Asrc + (size_t)t * 64;
    const bf16* gb = Bsrc + (size_t)t * 64;
    char* da = smem + buf*65536 + wid*1024;
    char* db = smem + buf*65536 + 32768 + wid*1024;
#pragma unroll
    for (int j = 0; j < 4; ++j) {
      gl_lds16(ga + (size_t)(64*j) * K, da + j*8192);
      gl_lds16(gb + (size_t)(64*j) * K, db + j*8192);
    }
  };

  // ds_read addressing (r4-verified): row-base + XOR'd per-slice column
  const int swz = (lr & 7) << 4;
  const int c0 = (lkg * 16) ^ swz;         // k-slice 0 (k 0..31)
  const int c1 = (lkg * 16 + 64) ^ swz;    // k-slice 1 (k 32..63)
  const int aRow = wm*16384 + lr*128;              // + mf*2048
  const int bRow = 32768 + wn*8192 + lr*128;       // + nf*2048

  const f32x4 vzero = {0.f, 0.f, 0.f, 0.f};
  f32x4 acc[8][4];
#pragma unroll
  for (int ii = 0; ii < 8; ++ii)
#pragma unroll
    for (int j = 0; j < 4; ++j) acc[ii][j] = vzero;

  const int nt = K >> 6;               // 32 K-tiles of 64

  stage(0, 0);
  asm volatile("s_waitcnt vmcnt(0)" ::: "memory");
  SCHED0; BARRIER;

  for (int t = 0; t < nt; ++t) {
    const int buf = (t & 1) * 65536;
    bf16x8 a0[8], b0[4], a1[8], b1[4];

    // slice-0 fragment reads
#pragma unroll
    for (int mf = 0; mf < 8; ++mf)
      a0[mf] = *(const bf16x8*)(smem + buf + aRow + mf*2048 + c0);
#pragma unroll
    for (int nf = 0; nf < 4; ++nf)
      b0[nf] = *(const bf16x8*)(smem + buf + bRow + nf*2048 + c0);
    // next-tile staging (into the buffer last read at t-1)
    if (t + 1 < nt) stage(t + 1, (t & 1) ^ 1);
    PRIO1;
#pragma unroll
    for (int mf = 0; mf < 8; ++mf)
#pragma unroll
      for (int nf = 0; nf < 4; ++nf)
        acc[mf][nf] = mfma16(a0[mf], b0[nf], acc[mf][nf]);
    PRIO0;
    // slice-1 fragment reads (compiler interleaves these into MFMA0)
#pragma unroll
    for (int mf = 0; mf < 8; ++mf)
      a1[mf] = *(const bf16x8*)(smem + buf + aRow + mf*2048 + c1);
#pragma unroll
    for (int nf = 0; nf < 4; ++nf)
      b1[nf] = *(const bf16x8*)(smem + buf + bRow + nf*2048 + c1);
    PRIO1;
#pragma unroll
    for (int mf = 0; mf < 8; ++mf)
#pragma unroll
      for (int nf = 0; nf < 4; ++nf)
        acc[mf][nf] = mfma16(a1[mf], b1[nf], acc[mf][nf]);
    PRIO0;
    // stage(t+1) must have landed before any wave reads buf^1 at t+1
    asm volatile("s_waitcnt vmcnt(0)" ::: "memory");
    SCHED0;
    BARRIER;
  }

  if constexpr (EPI == 1) {
    const float inv_sqrt_d = 0.08838834764831845f;  // 1/sqrt(128)
#pragma unroll
    for (int nf = 0; nf < 4; ++nf) {
      const int gcb = n0 + wn*64 + nf*16;           // wave-uniform, mult of 16
      const int section = gcb >> 11;                // 0=q 1=k 2=v
      const int cc = (gcb & 2047) + lr;
      const int h = cc >> 7, d = cc & 127;
#pragma unroll
      for (int mf = 0; mf < 8; ++mf) {
#pragma unroll
        for (int reg = 0; reg < 4; ++reg) {
          const int grow = m0 + wm*128 + mf*16 + lkg*4 + reg;
          const int bidx = grow >> 11, lseq = grow & 2047;
          float val = acc[mf][nf][reg];
          if (section < 2) {
            float p = __shfl_xor(val, 1);           // RoPE pair partner
            const int fi = d >> 1;
            float cv = cosT[(size_t)lseq * 64 + fi];
            float sv = sinT[(size_t)lseq * 64 + fi];
            float r = (d & 1) ? fmaf(p, sv, val * cv)
                              : fmaf(val, cv, -p * sv);
            if (section == 0) {
              r *= inv_sqrt_d;
              Qb[((size_t)(bidx*NHEAD + h) * LL + lseq) * HDIM + d] = __float2bfloat16(r);
            } else {
              Kb[((size_t)(bidx*NHEAD + h) * LL + lseq) * HDIM + d] = __float2bfloat16(r);
            }
          } else {
            VTb[((size_t)(bidx*NHEAD + h) * HDIM + d) * LL + lseq] = __float2bfloat16(val);
          }
        }
      }
    }
  } else {
#pragma unroll
    for (int nf = 0; nf < 4; ++nf) {
      const int gcol = n0 + wn*64 + nf*16 + lr;
      const float bv = bias[gcol];
#pragma unroll
      for (int mf = 0; mf < 8; ++mf) {
#pragma unroll
        for (int reg = 0; reg < 4; ++reg) {
          const int grow = m0 + wm*128 + mf*16 + lkg*4 + reg;
          Cout[(size_t)grow * N + gcol] = acc[mf][nf][reg] + bv;
        }
      }
    }
  }
}

// ====== 128x128 GEMM, BK=32, 3-buffer, 3 blocks/CU (r12-exact; GEMM2) ======
template<int EPI>
__global__ __launch_bounds__(512, 4)
void k_gemmP(const bf16* __restrict__ A, const bf16* __restrict__ BT,
             int M, int N, int K,
             float* __restrict__ Cout, const float* __restrict__ bias,
             const float* __restrict__ unused1, const float* __restrict__ unused2)
{
  constexpr int ABUF = 8192;
  constexpr int BBUF = 8192;
  constexpr int AREG = 3 * ABUF;       // 24576
  extern __shared__ char smem[];       // 49152 B

  const int tid = threadIdx.x;
  const int wid = tid >> 6, lane = tid & 63;
  const int wm = wid >> 2, wn = wid & 3;
  const int lr = lane & 15, lkg = lane >> 4;

  const int nbx = N >> 7;
  const int xcd = blockIdx.x & 7;
  const int i   = blockIdx.x >> 3;
  const int m0 = (((xcd >> 1) << 3) + (i & 7)) << 7;
  const int n0 = ((xcd & 1) * (nbx >> 1) + (i >> 3)) << 7;

  const int scol = ((lane & 3) ^ ((lane >> 3) & 3)) * 8;
  const bf16* Asrc = A  + (size_t)(m0 + wid*16 + (lane >> 2)) * K + scol;
  const bf16* Bsrc = BT + (size_t)(n0 + wid*16 + (lane >> 2)) * K + scol;

  auto stageA = [&](int t) {
    gl_lds16(Asrc + t*32, smem + (t % 3)*ABUF + wid*1024);
  };
  auto stageB = [&](int t) {
    gl_lds16(Bsrc + t*32, smem + AREG + (t % 3)*BBUF + wid*1024);
  };

  const int slotX = (lkg ^ ((lr >> 1) & 3)) * 16;
  const int aBase = wm*4096 + lr*64 + slotX;
  const int bBase = wn*2048 + lr*64 + slotX;

  const f32x4 vzero = {0.f, 0.f, 0.f, 0.f};
  f32x4 acc[4][2];
#pragma unroll
  for (int ii = 0; ii < 4; ++ii)
#pragma unroll
    for (int j = 0; j < 2; ++j) acc[ii][j] = vzero;

  const int nt = K >> 5;

  stageA(0); stageB(0); stageA(1); stageB(1);
  asm volatile("s_waitcnt vmcnt(2)" ::: "memory");
  SCHED0; BARRIER;

  for (int t = 0; t < nt; ++t) {
    const int bufA = (t % 3) * ABUF;
    const int bufB = AREG + (t % 3) * BBUF;
    const int ts   = (t + 2 < nt) ? t + 2 : nt - 1;
    bf16x8 aFr[4], bFr[2];

#pragma unroll
    for (int mf = 0; mf < 4; ++mf)
      aFr[mf] = *(const bf16x8*)(smem + bufA + aBase + mf*1024);
#pragma unroll
    for (int nf = 0; nf < 2; ++nf)
      bFr[nf] = *(const bf16x8*)(smem + bufB + bBase + nf*1024);
    stageA(ts); stageB(ts);

    asm volatile("s_waitcnt lgkmcnt(0)" ::: "memory");
    SCHED0;
    PRIO1;
#pragma unroll
    for (int mf = 0; mf < 4; ++mf)
#pragma unroll
      for (int nf = 0; nf < 2; ++nf)
        acc[mf][nf] = mfma16(aFr[mf], bFr[nf], acc[mf][nf]);
    PRIO0;
    asm volatile("s_waitcnt vmcnt(2)" ::: "memory");
    SCHED0;
    BARRIER;
  }

#pragma unroll
  for (int nf = 0; nf < 2; ++nf) {
    const int gcol = n0 + wn*32 + nf*16 + lr;
    const float bv = bias[gcol];
#pragma unroll
    for (int mf = 0; mf < 4; ++mf) {
#pragma unroll
      for (int reg = 0; reg < 4; ++reg) {
        const int grow = m0 + wm*64 + mf*16 + lkg*4 + reg;
        Cout[(size_t)grow * N + gcol] = acc[mf][nf][reg] + bv;
      }
    }
  }
}

// ---------------- flash attention (r14): swapped QK^T, lane-local softmax ----
__global__ __launch_bounds__(256, 2)
void k_attn(const bf16* __restrict__ Qb, const bf16* __restrict__ Kb,
            const bf16* __restrict__ VTb, bf16* __restrict__ attnA)
{
  __shared__ bf16 Ks[64][136];
  __shared__ bf16 Vs[128][72];
  __shared__ bf16 Ps[4][32][72];

  const int bh  = blockIdx.y;
  const int bx  = blockIdx.x;                 // 0..7
  const int tid = threadIdx.x;
  const int wid = tid >> 6, lane = tid & 63;
  const int lr  = lane & 15, lkg = lane >> 4;

  const bf16* Qh = Qb  + (size_t)bh * LL * HDIM;
  const bf16* Kh = Kb  + (size_t)bh * LL * HDIM;
  const bf16* Vh = VTb + (size_t)bh * HDIM * LL;
  const int b = bh >> 4, h = bh & 15;
  const f32x4 vzero = {0.f, 0.f, 0.f, 0.f};

  for (int pp = 0; pp < 2; ++pp) {
    const int qt  = pp ? bx : (15 - bx);      // heavy tile first
    const int Q0  = qt * 128;
    const int q0w = Q0 + wid * 32;

    bf16x8 qf[2][4];
#pragma unroll
    for (int qr = 0; qr < 2; ++qr)
#pragma unroll
      for (int kk = 0; kk < 4; ++kk)
        qf[qr][kk] = *(const bf16x8*)(Qh + (size_t)(q0w + qr*16 + lr) * HDIM + kk*32 + lkg*8);

    f32x4 oacc[2][8];
#pragma unroll
    for (int qr = 0; qr < 2; ++qr)
#pragma unroll
      for (int db = 0; db < 8; ++db) oacc[qr][db] = vzero;
    float ml[2] = {-INFINITY, -INFINITY};
    float ll[2] = {0.f, 0.f};

    const int NT = Q0 / 64 + 2;
    bf16x8 kpre[4], vpre[4];
#pragma unroll
    for (int j = 0; j < 4; ++j) {
      const int c = j*256 + tid;
      kpre[j] = *(const bf16x8*)(Kh + (size_t)(c >> 4) * HDIM + (c & 15) * 8);
      vpre[j] = *(const bf16x8*)(Vh + (size_t)(c >> 3) * LL + (c & 7) * 8);
    }

    for (int kt = 0; kt < NT; ++kt) {
      const int kbase = kt * 64;
      __syncthreads();
#pragma unroll
      for (int j = 0; j < 4; ++j) {
        const int c = j*256 + tid;
        *(bf16x8*)&Ks[c >> 4][(c & 15) * 8] = kpre[j];
        *(bf16x8*)&Vs[c >> 3][(c & 7) * 8]  = vpre[j];
      }
      __syncthreads();
      if (kt + 1 < NT) {
#pragma unroll
        for (int j = 0; j < 4; ++j) {
          const int c = j*256 + tid;
          kpre[j] = *(const bf16x8*)(Kh + (size_t)((kt+1)*64 + (c >> 4)) * HDIM + (c & 15) * 8);
          vpre[j] = *(const bf16x8*)(Vh + (size_t)(c >> 3) * LL + (kt+1)*64 + (c & 7) * 8);
        }
      }
      if (kbase <= q0w + 31) {
        f32x4 s2[2][4];
#pragma unroll
        for (int qr = 0; qr < 2; ++qr)
#pragma unroll
          for (int c = 0; c < 4; ++c) s2[qr][c] = vzero;
#pragma unroll
        for (int c = 0; c < 4; ++c) {
          bf16x8 kf[4];
#pragma unroll
          for (int kk = 0; kk < 4; ++kk)
            kf[kk] = *(const bf16x8*)&Ks[c*16 + lr][kk*32 + lkg*8];
#pragma unroll
          for (int qr = 0; qr < 2; ++qr)
#pragma unroll
            for (int kk = 0; kk < 4; ++kk)
              s2[qr][c] = mfma16(kf[kk], qf[qr][kk], s2[qr][c]);
        }
#pragma unroll
        for (int qr = 0; qr < 2; ++qr) {
          const int qrow = q0w + qr*16 + lr;
          float pv[4][4];
#pragma unroll
          for (int c = 0; c < 4; ++c)
#pragma unroll
            for (int reg = 0; reg < 4; ++reg) {
              const int kv = kbase + c*16 + lkg*4 + reg;
              pv[c][reg] = (kv <= qrow) ? s2[qr][c][reg] : -INFINITY;
            }
          float tm = pv[0][0];
#pragma unroll
          for (int c = 0; c < 4; ++c)
#pragma unroll
            for (int reg = 0; reg < 4; ++reg)
              if (c || reg) tm = fmaxf(tm, pv[c][reg]);
          tm = fmaxf(tm, __shfl_xor(tm, 16));
          tm = fmaxf(tm, __shfl_xor(tm, 32));
          const float mnew = fmaxf(ml[qr], tm);
          const float scl  = __expf(ml[qr] - mnew);
          ml[qr] = mnew;
          float rs = 0.f;
#pragma unroll
          for (int c = 0; c < 4; ++c)
#pragma unroll
            for (int reg = 0; reg < 4; ++reg) {
              pv[c][reg] = __expf(pv[c][reg] - mnew);
              rs += pv[c][reg];
            }
          rs += __shfl_xor(rs, 16);
          rs += __shfl_xor(rs, 32);
          ll[qr] = ll[qr] * scl + rs;
#pragma unroll
          for (int c = 0; c < 4; ++c) {
            unsigned lo = bfu(pv[c][0]) | (bfu(pv[c][1]) << 16);
            unsigned hi = bfu(pv[c][2]) | (bfu(pv[c][3]) << 16);
            *(uint2*)&Ps[wid][qr*16 + lr][c*16 + lkg*4] = make_uint2(lo, hi);
          }
          float sr[4];
#pragma unroll
          for (int reg = 0; reg < 4; ++reg) sr[reg] = __shfl(scl, lkg*4 + reg);
#pragma unroll
          for (int db = 0; db < 8; ++db) {
            oacc[qr][db][0] *= sr[0]; oacc[qr][db][1] *= sr[1];
            oacc[qr][db][2] *= sr[2]; oacc[qr][db][3] *= sr[3];
          }
        }
        asm volatile("s_waitcnt lgkmcnt(0)" ::: "memory");
        __builtin_amdgcn_sched_barrier(0);
        bf16x8 pf[2][2];
#pragma unroll
        for (int qr = 0; qr < 2; ++qr)
#pragma unroll
          for (int k2 = 0; k2 < 2; ++k2)
            pf[qr][k2] = *(const bf16x8*)&Ps[wid][qr*16 + lr][k2*32 + lkg*8];
#pragma unroll
        for (int db = 0; db < 8; ++db) {
          bf16x8 vf0 = *(const bf16x8*)&Vs[db*16 + lr][lkg*8];
          bf16x8 vf1 = *(const bf16x8*)&Vs[db*16 + lr][32 + lkg*8];
#pragma unroll
          for (int qr = 0; qr < 2; ++qr) {
            oacc[qr][db] = mfma16(pf[qr][0], vf0, oacc[qr][db]);
            oacc[qr][db] = mfma16(pf[qr][1], vf1, oacc[qr][db]);
          }
        }
      }
    }

#pragma unroll
    for (int qr = 0; qr < 2; ++qr) {
      const float myinv = 1.0f / ll[qr];
      float li[4];
#pragma unroll
      for (int reg = 0; reg < 4; ++reg) li[reg] = __shfl(myinv, lkg*4 + reg);
#pragma unroll
      for (int reg = 0; reg < 4; ++reg) {
        const int row = q0w + qr*16 + lkg*4 + reg;
        bf16* dst = attnA + ((size_t)(b*LL + row)) * MODEL + h * HDIM;
#pragma unroll
        for (int db = 0; db < 8; ++db)
          dst[db*16 + lr] = __float2bfloat16(oacc[qr][db][reg] * li[reg]);
      }
    }
  }
}

// ---------------- launch ----------------
extern "C" void kernel_launch(void* const* d_in, const int* in_sizes, int n_in,
                              void* d_out, int out_size, void* d_ws, size_t ws_size,
                              hipStream_t stream)
{
  const float* x    = (const float*)d_in[0];
  const float* cosT = (const float*)d_in[1];
  const float* sinT = (const float*)d_in[2];
  const float* Wqkv = (const float*)d_in[3];
  const float* Wc   = (const float*)d_in[4];
  const float* bc   = (const float*)d_in[5];
  float* out = (float*)d_out;

  // workspace layout (bytes):
  //   x16    @ 0         : 16,777,216   (reused as attnA later)
  //   WqkvT  @ 16777216  : 25,165,824
  //   WcT    @ 41943040  :  8,388,608
  //   Qb     @ 50331648  : 16,777,216
  //   Kb     @ 67108864  : 16,777,216
  //   VTb    @ 83886080  : 16,777,216   -> total 100,663,296 B
  if (ws_size < 100663296u) return;
  char* w = (char*)d_ws;
  bf16* x16   = (bf16*)(w);
  bf16* WqkvT = (bf16*)(w + (size_t)16777216);
  bf16* WcT   = (bf16*)(w + (size_t)41943040);
  bf16* Qb    = (bf16*)(w + (size_t)50331648);
  bf16* Kb    = (bf16*)(w + (size_t)67108864);
  bf16* VTb   = (bf16*)(w + (size_t)83886080);
  bf16* attnA = x16;   // overlay: x16 dead after GEMM1

  // allow dynamic LDS (idempotent; not a stream op -> capture-safe)
  hipFuncSetAttribute(reinterpret_cast<const void*>(&k_gemmX<1>),
                      hipFuncAttributeMaxDynamicSharedMemorySize, 131072);
  hipFuncSetAttribute(reinterpret_cast<const void*>(&k_gemmP<2>),
                      hipFuncAttributeMaxDynamicSharedMemorySize, 49152);

  k_cvt<<<(MTOT*MODEL/4 + 255)/256, 256, 0, stream>>>(x, x16, MTOT*MODEL/4);
  k_transpose<<<dim3(N1/32,    MODEL/32), 256, 0, stream>>>(Wqkv, WqkvT, MODEL, N1);
  k_transpose<<<dim3(MODEL/32, MODEL/32), 256, 0, stream>>>(Wc,   WcT,   MODEL, MODEL);

  // grid 16*24 = 384 blocks (1 block/CU, 1.5 rounds)
  k_gemmX<1><<<(MTOT/256)*(N1/256), 512, 131072, stream>>>(
      x16, WqkvT, MTOT, N1, MODEL,
      nullptr, nullptr, Qb, Kb, VTb, cosT, sinT);

  // grid 8*32 = 256 blocks, uniform 17 tile-units each
  k_attn<<<dim3(8, BB*NHEAD), 256, 0, stream>>>(Qb, Kb, VTb, attnA);

  // grid 16*32 = 512 blocks (3 blocks/CU, r12-exact)
  k_gemmP<2><<<(MODEL/128)*(MTOT/128), 512, 49152, stream>>>(
      attnA, WcT, MTOT, MODEL, MODEL,
      out, bc, nullptr, nullptr);
}

// Round 16
// 296.759 us; speedup vs baseline: 1.0656x; 1.0656x over previous
//
#include <hip/hip_runtime.h>
#include <hip/hip_bf16.h>

#define MODEL 2048
#define NHEAD 16
#define HDIM  128
#define BB    2
#define LL    2048
#define N1    (3*MODEL)      // 6144
#define MTOT  (BB*LL)        // 4096

typedef __hip_bfloat16 bf16;
typedef __attribute__((ext_vector_type(8))) short bf16x8;
typedef __attribute__((ext_vector_type(4))) float f32x4;

static __device__ __forceinline__ f32x4 mfma16(bf16x8 a, bf16x8 b, f32x4 c) {
  return __builtin_amdgcn_mfma_f32_16x16x32_bf16(a, b, c, 0, 0, 0);
}

// async global->LDS DMA, 16B per lane; LDS base wave-uniform, dest linear
static __device__ __forceinline__ void gl_lds16(const void* g, void* l) {
  __builtin_amdgcn_global_load_lds(
      (const __attribute__((address_space(1))) unsigned int*)g,
      (__attribute__((address_space(3))) unsigned int*)l, 16, 0, 0);
}

static __device__ __forceinline__ unsigned bfu(float x) {
  bf16 b = __float2bfloat16(x);
  return (unsigned)*reinterpret_cast<unsigned short*>(&b);
}

#define BARRIER __builtin_amdgcn_s_barrier()
#define SCHED0  __builtin_amdgcn_sched_barrier(0)
#define PRIO1 __builtin_amdgcn_s_setprio(1)
#define PRIO0 __builtin_amdgcn_s_setprio(0)

// ---------------- prep: f32 -> bf16 (vectorized x4) ----------------
__global__ void k_cvt(const float* __restrict__ in, bf16* __restrict__ out, int n4) {
  int i = blockIdx.x * blockDim.x + threadIdx.x;
  if (i < n4) {
    float4 v = ((const float4*)in)[i];
    bf16* o = out + (size_t)i * 4;
    o[0] = __float2bfloat16(v.x);
    o[1] = __float2bfloat16(v.y);
    o[2] = __float2bfloat16(v.z);
    o[3] = __float2bfloat16(v.w);
  }
}

// ---------------- prep: transpose f32 [R][C] -> bf16 [C][R] ----------------
__global__ __launch_bounds__(256)
void k_transpose(const float* __restrict__ in, bf16* __restrict__ out, int R, int C) {
  __shared__ float t[32][33];
  const int c0 = blockIdx.x * 32, r0 = blockIdx.y * 32;
  const int tx = threadIdx.x & 31;
  const int ty = threadIdx.x >> 5;   // 0..7
#pragma unroll
  for (int i = 0; i < 4; ++i)
    t[ty + 8*i][tx] = in[(size_t)(r0 + ty + 8*i) * C + c0 + tx];
  __syncthreads();
#pragma unroll
  for (int i = 0; i < 4; ++i)
    out[(size_t)(c0 + ty + 8*i) * R + r0 + tx] = __float2bfloat16(t[tx][ty + 8*i]);
}

// ====== 128x128 GEMM, BK=32, 3-buffer pipeline, 3 blocks/CU (r16) ======
// r12-proven skeleton: 8 waves 2Mx4N, lockstep tile, distributed staging +
// collective barrier per tile [r8 lesson], mod-3 rotation with depth-2
// staging [r12 safety], slot swizzle [r6, 0-conflict], square XCD chunking
// [r12: per-XCD A panel L2-fits].
// r16 change: REMOVED the explicit lgkmcnt(0)+sched_barrier before the MFMA
// cluster. The compiler inserts fine-grained lgkmcnt(N) per ds_read->MFMA
// dep (m97 evidence), so the first MFMAs start while the remaining frags
// drain -- the hand-written full drain serialized the LDS and matrix pipes
// (r12 counters: pipe-busy SUM ~= measured cycles -> no overlap).
// vmcnt(2)+barrier at tile end kept: publishes tile t+1 collectively.
// EPI==1: RoPE + scatter Q/K row-major + V^T ; EPI==2: bias + f32 out.
template<int EPI>
__global__ __launch_bounds__(512, 4)
void k_gemmP(const bf16* __restrict__ A, const bf16* __restrict__ BT,
             int M, int N, int K,
             float* __restrict__ Cout, const float* __restrict__ bias,
             bf16* __restrict__ Qb, bf16* __restrict__ Kb, bf16* __restrict__ VTb,
             const float* __restrict__ cosT, const float* __restrict__ sinT)
{
  constexpr int ABUF = 8192;           // one A tile (128 rows x 64B)
  constexpr int BBUF = 8192;
  constexpr int AREG = 3 * ABUF;       // 24576
  extern __shared__ char smem[];       // 49152 B

  const int tid = threadIdx.x;
  const int wid = tid >> 6, lane = tid & 63;
  const int wm = wid >> 2, wn = wid & 3;       // wave grid 2(M) x 4(N)
  const int lr = lane & 15, lkg = lane >> 4;

  // XCD chunk map (bid%8 = XCD): XCD=(mquarter, nhalf) owns an
  // 8 m-tile x (nbx/2) n-tile chunk, m-inner traversal (A panel L2-fits).
  const int nbx = N >> 7;
  const int xcd = blockIdx.x & 7;
  const int i   = blockIdx.x >> 3;
  const int m0 = (((xcd >> 1) << 3) + (i & 7)) << 7;
  const int n0 = ((xcd & 1) * (nbx >> 1) + (i >> 3)) << 7;

  // staging: wave wid owns 16 rows; source slot carries inverse swizzle
  const int scol = ((lane & 3) ^ ((lane >> 3) & 3)) * 8;   // bf16 elems
  const bf16* Asrc = A  + (size_t)(m0 + wid*16 + (lane >> 2)) * K + scol;
  const bf16* Bsrc = BT + (size_t)(n0 + wid*16 + (lane >> 2)) * K + scol;

  auto stageA = [&](int t) {
    gl_lds16(Asrc + t*32, smem + (t % 3)*ABUF + wid*1024);
  };
  auto stageB = [&](int t) {
    gl_lds16(Bsrc + t*32, smem + AREG + (t % 3)*BBUF + wid*1024);
  };

  // ds_read fragment bases (row = 64B, slot XOR-swizzled by row bits 1-2)
  const int slotX = (lkg ^ ((lr >> 1) & 3)) * 16;
  const int aBase = wm*4096 + lr*64 + slotX;   // rows wm*64 + mf*16 + lr
  const int bBase = wn*2048 + lr*64 + slotX;   // rows wn*32 + nf*16 + lr

  const f32x4 vzero = {0.f, 0.f, 0.f, 0.f};
  f32x4 acc[4][2];
#pragma unroll
  for (int ii = 0; ii < 4; ++ii)
#pragma unroll
    for (int j = 0; j < 2; ++j) acc[ii][j] = vzero;

  const int nt = K >> 5;              // K-tiles of 32 (>= 3)

  // prologue: stage tiles 0,1 -> wait until tile 0's 2 loads complete
  stageA(0); stageB(0); stageA(1); stageB(1);
  asm volatile("s_waitcnt vmcnt(2)" ::: "memory");
  SCHED0; BARRIER;

  for (int t = 0; t < nt; ++t) {
    const int bufA = (t % 3) * ABUF;
    const int bufB = AREG + (t % 3) * BBUF;
    const int ts   = (t + 2 < nt) ? t + 2 : nt - 1;   // clamp: same-data dup
    bf16x8 aFr[4], bFr[2];

#pragma unroll
    for (int mf = 0; mf < 4; ++mf)
      aFr[mf] = *(const bf16x8*)(smem + bufA + aBase + mf*1024);
#pragma unroll
    for (int nf = 0; nf < 2; ++nf)
      bFr[nf] = *(const bf16x8*)(smem + bufB + bBase + nf*1024);
    stageA(ts); stageB(ts);

    // NOTE (r16): no explicit lgkm drain here -- compiler emits fine-grained
    // lgkmcnt(N) per frag->MFMA dep, overlapping ds_read drain with MFMAs.
    PRIO1;
#pragma unroll
    for (int mf = 0; mf < 4; ++mf)
#pragma unroll
      for (int nf = 0; nf < 2; ++nf)
        acc[mf][nf] = mfma16(aFr[mf], bFr[nf], acc[mf][nf]);
    PRIO0;
    // complete tile t+1's loads (only stage(t+2)'s 2 loads stay in flight)
    asm volatile("s_waitcnt vmcnt(2)" ::: "memory");
    SCHED0;
    BARRIER;                          // collective: tile t+1 visible to all
  }

  if constexpr (EPI == 1) {
    const float inv_sqrt_d = 0.08838834764831845f;  // 1/sqrt(128)
#pragma unroll
    for (int nf = 0; nf < 2; ++nf) {
      const int gcb = n0 + wn*32 + nf*16;           // wave-uniform, mult of 16
      const int section = gcb >> 11;                // 0=q 1=k 2=v
      const int cc = (gcb & 2047) + lr;
      const int h = cc >> 7, d = cc & 127;
#pragma unroll
      for (int mf = 0; mf < 4; ++mf) {
#pragma unroll
        for (int reg = 0; reg < 4; ++reg) {
          const int grow = m0 + wm*64 + mf*16 + lkg*4 + reg;
          const int bidx = grow >> 11, lseq = grow & 2047;
          float val = acc[mf][nf][reg];
          if (section < 2) {
            float p = __shfl_xor(val, 1);           // RoPE pair partner
            const int fi = d >> 1;
            float cv = cosT[(size_t)lseq * 64 + fi];
            float sv = sinT[(size_t)lseq * 64 + fi];
            float r = (d & 1) ? fmaf(p, sv, val * cv)
                              : fmaf(val, cv, -p * sv);
            if (section == 0) {
              r *= inv_sqrt_d;
              Qb[((size_t)(bidx*NHEAD + h) * LL + lseq) * HDIM + d] = __float2bfloat16(r);
            } else {
              Kb[((size_t)(bidx*NHEAD + h) * LL + lseq) * HDIM + d] = __float2bfloat16(r);
            }
          } else {
            VTb[((size_t)(bidx*NHEAD + h) * HDIM + d) * LL + lseq] = __float2bfloat16(val);
          }
        }
      }
    }
  } else {
#pragma unroll
    for (int nf = 0; nf < 2; ++nf) {
      const int gcol = n0 + wn*32 + nf*16 + lr;
      const float bv = bias[gcol];
#pragma unroll
      for (int mf = 0; mf < 4; ++mf) {
#pragma unroll
        for (int reg = 0; reg < 4; ++reg) {
          const int grow = m0 + wm*64 + mf*16 + lkg*4 + reg;
          Cout[(size_t)grow * N + gcol] = acc[mf][nf][reg] + bv;
        }
      }
    }
  }
}

// ---------------- flash attention (r14-exact): swapped QK^T ----------------
// s2 = mfma(K,Q): lane (lr,lkg) holds S[q=lr][kv=c*16+lkg*4+reg] -> row
// softmax is 16 lane-local values + 2 shfl. P packs 4 bf16 -> b64 writes.
// Balanced q-tile pairing (r9): block bx does (15-bx) then bx.
__global__ __launch_bounds__(256, 2)
void k_attn(const bf16* __restrict__ Qb, const bf16* __restrict__ Kb,
            const bf16* __restrict__ VTb, bf16* __restrict__ attnA)
{
  __shared__ bf16 Ks[64][136];
  __shared__ bf16 Vs[128][72];
  __shared__ bf16 Ps[4][32][72];

  const int bh  = blockIdx.y;
  const int bx  = blockIdx.x;                 // 0..7
  const int tid = threadIdx.x;
  const int wid = tid >> 6, lane = tid & 63;
  const int lr  = lane & 15, lkg = lane >> 4;

  const bf16* Qh = Qb  + (size_t)bh * LL * HDIM;
  const bf16* Kh = Kb  + (size_t)bh * LL * HDIM;
  const bf16* Vh = VTb + (size_t)bh * HDIM * LL;
  const int b = bh >> 4, h = bh & 15;
  const f32x4 vzero = {0.f, 0.f, 0.f, 0.f};

  for (int pp = 0; pp < 2; ++pp) {
    const int qt  = pp ? bx : (15 - bx);      // heavy tile first
    const int Q0  = qt * 128;
    const int q0w = Q0 + wid * 32;

    bf16x8 qf[2][4];
#pragma unroll
    for (int qr = 0; qr < 2; ++qr)
#pragma unroll
      for (int kk = 0; kk < 4; ++kk)
        qf[qr][kk] = *(const bf16x8*)(Qh + (size_t)(q0w + qr*16 + lr) * HDIM + kk*32 + lkg*8);

    f32x4 oacc[2][8];
#pragma unroll
    for (int qr = 0; qr < 2; ++qr)
#pragma unroll
      for (int db = 0; db < 8; ++db) oacc[qr][db] = vzero;
    float ml[2] = {-INFINITY, -INFINITY};
    float ll[2] = {0.f, 0.f};

    const int NT = Q0 / 64 + 2;
    bf16x8 kpre[4], vpre[4];
#pragma unroll
    for (int j = 0; j < 4; ++j) {
      const int c = j*256 + tid;
      kpre[j] = *(const bf16x8*)(Kh + (size_t)(c >> 4) * HDIM + (c & 15) * 8);
      vpre[j] = *(const bf16x8*)(Vh + (size_t)(c >> 3) * LL + (c & 7) * 8);
    }

    for (int kt = 0; kt < NT; ++kt) {
      const int kbase = kt * 64;
      __syncthreads();
#pragma unroll
      for (int j = 0; j < 4; ++j) {
        const int c = j*256 + tid;
        *(bf16x8*)&Ks[c >> 4][(c & 15) * 8] = kpre[j];
        *(bf16x8*)&Vs[c >> 3][(c & 7) * 8]  = vpre[j];
      }
      __syncthreads();
      if (kt + 1 < NT) {
#pragma unroll
        for (int j = 0; j < 4; ++j) {
          const int c = j*256 + tid;
          kpre[j] = *(const bf16x8*)(Kh + (size_t)((kt+1)*64 + (c >> 4)) * HDIM + (c & 15) * 8);
          vpre[j] = *(const bf16x8*)(Vh + (size_t)(c >> 3) * LL + (kt+1)*64 + (c & 7) * 8);
        }
      }
      if (kbase <= q0w + 31) {
        f32x4 s2[2][4];
#pragma unroll
        for (int qr = 0; qr < 2; ++qr)
#pragma unroll
          for (int c = 0; c < 4; ++c) s2[qr][c] = vzero;
#pragma unroll
        for (int c = 0; c < 4; ++c) {
          bf16x8 kf[4];
#pragma unroll
          for (int kk = 0; kk < 4; ++kk)
            kf[kk] = *(const bf16x8*)&Ks[c*16 + lr][kk*32 + lkg*8];
#pragma unroll
          for (int qr = 0; qr < 2; ++qr)
#pragma unroll
            for (int kk = 0; kk < 4; ++kk)
              s2[qr][c] = mfma16(kf[kk], qf[qr][kk], s2[qr][c]);
        }
#pragma unroll
        for (int qr = 0; qr < 2; ++qr) {
          const int qrow = q0w + qr*16 + lr;
          float pv[4][4];
#pragma unroll
          for (int c = 0; c < 4; ++c)
#pragma unroll
            for (int reg = 0; reg < 4; ++reg) {
              const int kv = kbase + c*16 + lkg*4 + reg;
              pv[c][reg] = (kv <= qrow) ? s2[qr][c][reg] : -INFINITY;
            }
          float tm = pv[0][0];
#pragma unroll
          for (int c = 0; c < 4; ++c)
#pragma unroll
            for (int reg = 0; reg < 4; ++reg)
              if (c || reg) tm = fmaxf(tm, pv[c][reg]);
          tm = fmaxf(tm, __shfl_xor(tm, 16));
          tm = fmaxf(tm, __shfl_xor(tm, 32));
          const float mnew = fmaxf(ml[qr], tm);
          const float scl  = __expf(ml[qr] - mnew);
          ml[qr] = mnew;
          float rs = 0.f;
#pragma unroll
          for (int c = 0; c < 4; ++c)
#pragma unroll
            for (int reg = 0; reg < 4; ++reg) {
              pv[c][reg] = __expf(pv[c][reg] - mnew);
              rs += pv[c][reg];
            }
          rs += __shfl_xor(rs, 16);
          rs += __shfl_xor(rs, 32);
          ll[qr] = ll[qr] * scl + rs;
#pragma unroll
          for (int c = 0; c < 4; ++c) {
            unsigned lo = bfu(pv[c][0]) | (bfu(pv[c][1]) << 16);
            unsigned hi = bfu(pv[c][2]) | (bfu(pv[c][3]) << 16);
            *(uint2*)&Ps[wid][qr*16 + lr][c*16 + lkg*4] = make_uint2(lo, hi);
          }
          float sr[4];
#pragma unroll
          for (int reg = 0; reg < 4; ++reg) sr[reg] = __shfl(scl, lkg*4 + reg);
#pragma unroll
          for (int db = 0; db < 8; ++db) {
            oacc[qr][db][0] *= sr[0]; oacc[qr][db][1] *= sr[1];
            oacc[qr][db][2] *= sr[2]; oacc[qr][db][3] *= sr[3];
          }
        }
        asm volatile("s_waitcnt lgkmcnt(0)" ::: "memory");
        __builtin_amdgcn_sched_barrier(0);
        bf16x8 pf[2][2];
#pragma unroll
        for (int qr = 0; qr < 2; ++qr)
#pragma unroll
          for (int k2 = 0; k2 < 2; ++k2)
            pf[qr][k2] = *(const bf16x8*)&Ps[wid][qr*16 + lr][k2*32 + lkg*8];
#pragma unroll
        for (int db = 0; db < 8; ++db) {
          bf16x8 vf0 = *(const bf16x8*)&Vs[db*16 + lr][lkg*8];
          bf16x8 vf1 = *(const bf16x8*)&Vs[db*16 + lr][32 + lkg*8];
#pragma unroll
          for (int qr = 0; qr < 2; ++qr) {
            oacc[qr][db] = mfma16(pf[qr][0], vf0, oacc[qr][db]);
            oacc[qr][db] = mfma16(pf[qr][1], vf1, oacc[qr][db]);
          }
        }
      }
    }

#pragma unroll
    for (int qr = 0; qr < 2; ++qr) {
      const float myinv = 1.0f / ll[qr];
      float li[4];
#pragma unroll
      for (int reg = 0; reg < 4; ++reg) li[reg] = __shfl(myinv, lkg*4 + reg);
#pragma unroll
      for (int reg = 0; reg < 4; ++reg) {
        const int row = q0w + qr*16 + lkg*4 + reg;
        bf16* dst = attnA + ((size_t)(b*LL + row)) * MODEL + h * HDIM;
#pragma unroll
        for (int db = 0; db < 8; ++db)
          dst[db*16 + lr] = __float2bfloat16(oacc[qr][db][reg] * li[reg]);
      }
    }
  }
}

// ---------------- launch ----------------
extern "C" void kernel_launch(void* const* d_in, const int* in_sizes, int n_in,
                              void* d_out, int out_size, void* d_ws, size_t ws_size,
                              hipStream_t stream)
{
  const float* x    = (const float*)d_in[0];
  const float* cosT = (const float*)d_in[1];
  const float* sinT = (const float*)d_in[2];
  const float* Wqkv = (const float*)d_in[3];
  const float* Wc   = (const float*)d_in[4];
  const float* bc   = (const float*)d_in[5];
  float* out = (float*)d_out;

  // workspace layout (bytes):
  //   x16    @ 0         : 16,777,216   (reused as attnA later)
  //   WqkvT  @ 16777216  : 25,165,824
  //   WcT    @ 41943040  :  8,388,608
  //   Qb     @ 50331648  : 16,777,216
  //   Kb     @ 67108864  : 16,777,216
  //   VTb    @ 83886080  : 16,777,216   -> total 100,663,296 B
  if (ws_size < 100663296u) return;
  char* w = (char*)d_ws;
  bf16* x16   = (bf16*)(w);
  bf16* WqkvT = (bf16*)(w + (size_t)16777216);
  bf16* WcT   = (bf16*)(w + (size_t)41943040);
  bf16* Qb    = (bf16*)(w + (size_t)50331648);
  bf16* Kb    = (bf16*)(w + (size_t)67108864);
  bf16* VTb   = (bf16*)(w + (size_t)83886080);
  bf16* attnA = x16;   // overlay: x16 dead after GEMM1

  // allow 48KB dynamic LDS (idempotent; not a stream op -> capture-safe)
  hipFuncSetAttribute(reinterpret_cast<const void*>(&k_gemmP<1>),
                      hipFuncAttributeMaxDynamicSharedMemorySize, 49152);
  hipFuncSetAttribute(reinterpret_cast<const void*>(&k_gemmP<2>),
                      hipFuncAttributeMaxDynamicSharedMemorySize, 49152);

  k_cvt<<<(MTOT*MODEL/4 + 255)/256, 256, 0, stream>>>(x, x16, MTOT*MODEL/4);
  k_transpose<<<dim3(N1/32,    MODEL/32), 256, 0, stream>>>(Wqkv, WqkvT, MODEL, N1);
  k_transpose<<<dim3(MODEL/32, MODEL/32), 256, 0, stream>>>(Wc,   WcT,   MODEL, MODEL);

  // grid 48*32 = 1536 blocks (3 blocks/CU -> 2 exact rounds of 768)
  k_gemmP<1><<<(N1/128)*(MTOT/128), 512, 49152, stream>>>(
      x16, WqkvT, MTOT, N1, MODEL,
      nullptr, nullptr, Qb, Kb, VTb, cosT, sinT);

  // grid 8*32 = 256 blocks, uniform 17 tile-units each
  k_attn<<<dim3(8, BB*NHEAD), 256, 0, stream>>>(Qb, Kb, VTb, attnA);

  // grid 16*32 = 512 blocks
  k_gemmP<2><<<(MODEL/128)*(MTOT/128), 512, 49152, stream>>>(
      attnA, WcT, MTOT, MODEL, MODEL,
      out, bc, nullptr, nullptr, nullptr, nullptr, nullptr);
}